// Round 7
// baseline (116.205 us; speedup 1.0000x reference)
//
#include <hip/hip_runtime.h>

typedef __attribute__((ext_vector_type(8))) _Float16 f16x8;
typedef __attribute__((ext_vector_type(4))) _Float16 f16x4;
typedef __attribute__((ext_vector_type(4))) float   f32x4;

#define BATCH 16384
#define NFEAT 512
#define NCLS  1000
#define NLEAF 256
#define NINT  255
#define NPAD  1024
#define LDP   72    // staging LDS row stride (f16): 144B -> optimal 8-slot spread for b128
#define MUP   264   // mu LDS row stride (f16): 528B, 528/16=33 odd -> optimal spread
#define PSTR  257   // P LDS row stride (f32): breaks the 4-way bank conflict on P writes
#define CSTR  516   // C-assembly row stride (f32)

// ---- convert gate_w (255x512) -> f16 padded to 256x512 (row 255 = 0) ----
__global__ __launch_bounds__(256) void cvt_gw(const float4* __restrict__ in,
                                              f16x4* __restrict__ out) {
  int i = blockIdx.x * 256 + threadIdx.x;   // quad index, 32768 total
  int row = i >> 7;
  f16x4 o;
  if (row < NINT) {
    float4 v = in[i];
    o[0] = (_Float16)v.x; o[1] = (_Float16)v.y;
    o[2] = (_Float16)v.z; o[3] = (_Float16)v.w;
  } else {
    o[0] = o[1] = o[2] = o[3] = (_Float16)0.f;
  }
  out[i] = o;
}

// ---- softmax rows of leaf_logits (256x1000) -> distT[c][l] f16, rows 1000..1023 zeroed ----
__global__ __launch_bounds__(256) void softmax_t(const float* __restrict__ L,
                                                 _Float16* __restrict__ distT) {
  __shared__ float red[4];
  const int l = blockIdx.x, t = threadIdx.x;
  const int wave = t >> 6, lane = t & 63;
  float v[4];
  if (t < 250) {
    float4 f = *(const float4*)&L[(size_t)l * NCLS + t * 4];
    v[0] = f.x; v[1] = f.y; v[2] = f.z; v[3] = f.w;
  } else {
    v[0] = v[1] = v[2] = v[3] = -1e30f;
  }
  float mx = fmaxf(fmaxf(v[0], v[1]), fmaxf(v[2], v[3]));
#pragma unroll
  for (int s = 32; s; s >>= 1) mx = fmaxf(mx, __shfl_xor(mx, s));
  if (lane == 0) red[wave] = mx;
  __syncthreads();
  mx = fmaxf(fmaxf(red[0], red[1]), fmaxf(red[2], red[3]));
  __syncthreads();
  float e[4], sum = 0.f;
#pragma unroll
  for (int i = 0; i < 4; ++i) { e[i] = __expf(v[i] - mx); sum += e[i]; }
  if (t >= 250) { e[0] = e[1] = e[2] = e[3] = 0.f; sum = 0.f; }
#pragma unroll
  for (int s = 32; s; s >>= 1) sum += __shfl_xor(sum, s);
  if (lane == 0) red[wave] = sum;
  __syncthreads();
  sum = red[0] + red[1] + red[2] + red[3];
  float inv = 1.f / sum;
  if (t < 250) {
#pragma unroll
    for (int i = 0; i < 4; ++i)
      distT[(size_t)(t * 4 + i) * NLEAF + l] = (_Float16)(e[i] * inv);
  }
  if (t < NPAD - NCLS) distT[(size_t)(NCLS + t) * NLEAF + l] = (_Float16)0.f;
}

// ---- fused: gemm1 + sigmoid + tree + gemm2 with row-streaming epilogue ----
// BM=32 rows/block, 512 blocks, 512 threads (8 waves), 2 blocks/CU.
__global__ __launch_bounds__(512, 4)
void fused(const float* __restrict__ x, const _Float16* __restrict__ gwh,
           const float* __restrict__ gb, const _Float16* __restrict__ distT,
           float* __restrict__ out) {
  __shared__ union {
    struct { _Float16 A[32 * LDP]; _Float16 B[256 * LDP]; } s;  // 41,472 B
    float P[32 * PSTR];                                         // 32,896 B
    float C[16 * CSTR];                                         // 33,024 B
  } sm;
  __shared__ _Float16 sMu[32 * MUP];                            // 16,896 B
  // union 41,472 + 16,896 = 58,368 B -> 2 blocks/CU

  const int tid  = threadIdx.x;
  const int wave = tid >> 6, lane = tid & 63;
  const int ln15 = lane & 15, lhi = lane >> 4;
  const int wr = wave >> 2, wc = wave & 3;      // 2x4 waves: 16 rows x 64 cols
  const int r0 = blockIdx.x * 32;

  // bias preload (overlaps first staging latency)
  float bias_[4];
#pragma unroll
  for (int n = 0; n < 4; ++n) {
    int col = wc * 64 + n * 16 + ln15;
    bias_[n] = (col < NINT) ? gb[col] : 0.f;
  }

  // ---------------- phase 1: logits = x @ gwh^T ----------------
  f32x4 acc1[4] = {};
  const int arow = tid >> 4, acol = (tid & 15) * 4;  // A: 1 float4/thread
  const int brow = tid >> 3, bcol = (tid & 7) * 8;   // B: 4 uint4/thread

  float4 pa;
  uint4  pb[4];

#define P1_LOAD(k0)                                                              \
  {                                                                              \
    pa = *(const float4*)&x[(size_t)(r0 + arow) * NFEAT + (k0) + acol];          \
    _Pragma("unroll")                                                            \
    for (int i = 0; i < 4; ++i)                                                  \
      pb[i] = *(const uint4*)&gwh[(size_t)(i * 64 + brow) * NFEAT + (k0) + bcol];\
  }
#define P1_WRITE()                                                               \
  {                                                                              \
    f16x4 h;                                                                     \
    h[0] = (_Float16)pa.x; h[1] = (_Float16)pa.y;                                \
    h[2] = (_Float16)pa.z; h[3] = (_Float16)pa.w;                                \
    *(f16x4*)&sm.s.A[arow * LDP + acol] = h;                                     \
    _Pragma("unroll")                                                            \
    for (int i = 0; i < 4; ++i)                                                  \
      *(uint4*)&sm.s.B[(i * 64 + brow) * LDP + bcol] = pb[i];                    \
  }

  P1_LOAD(0);
  for (int k = 0; k < NFEAT / 64; ++k) {
    P1_WRITE();
    __syncthreads();
    if (k < NFEAT / 64 - 1) P1_LOAD((k + 1) * 64);   // next loads fly over MFMA
#pragma unroll
    for (int kk = 0; kk < 2; ++kk) {
      f16x8 a, b[4];
      a = *(const f16x8*)&sm.s.A[(wr * 16 + ln15) * LDP + kk * 32 + lhi * 8];
#pragma unroll
      for (int n = 0; n < 4; ++n)
        b[n] = *(const f16x8*)&sm.s.B[(wc * 64 + n * 16 + ln15) * LDP + kk * 32 + lhi * 8];
#pragma unroll
      for (int n = 0; n < 4; ++n)
        acc1[n] = __builtin_amdgcn_mfma_f32_16x16x32_f16(a, b[n], acc1[n], 0, 0, 0);
    }
    __syncthreads();
  }

  // ---------------- phase 2a: sigmoid -> P (LDS, stride 257) ----------------
#pragma unroll
  for (int n = 0; n < 4; ++n) {
    int col = wc * 64 + n * 16 + ln15;
#pragma unroll
    for (int j = 0; j < 4; ++j) {
      int rl = wr * 16 + lhi * 4 + j;
      float v = acc1[n][j] + bias_[n];
      sm.P[rl * PSTR + col] = 1.f / (1.f + __expf(-v));
    }
  }
  __syncthreads();

  // ---------------- phase 2b: tree product -> sMu ----------------
  const int lf = lane * 4;
#pragma unroll
  for (int rr = 0; rr < 4; ++rr) {
    int row = wave * 4 + rr;
    const float* p = &sm.P[row * PSTR];
    float pre = 1.f;
#pragma unroll
    for (int d = 0; d < 6; ++d) {
      int node = (1 << d) - 1 + (lf >> (8 - d));
      int bit  = (lf >> (7 - d)) & 1;
      float g = p[node];
      pre *= bit ? g : (1.f - g);
    }
    float g6  = p[63 + lane];
    float g7a = p[127 + 2 * lane];
    float g7b = p[128 + 2 * lane];
    f16x4 o;
    o[0] = (_Float16)(pre * (1.f - g6) * (1.f - g7a));
    o[1] = (_Float16)(pre * (1.f - g6) * g7a);
    o[2] = (_Float16)(pre * g6 * (1.f - g7b));
    o[3] = (_Float16)(pre * g6 * g7b);
    *(f16x4*)&sMu[row * MUP + lf] = o;
  }
  __syncthreads();

  // ---------------- phase 3: out = mu @ distT^T, row-streaming epilogue ----------------
  const int wr2 = wave >> 2, wc2 = wave & 3;   // rows wr2*16..+16, col-block wc2*128
  f16x8 aa[8];
#pragma unroll
  for (int kk = 0; kk < 8; ++kk)
    aa[kk] = *(const f16x8*)&sMu[(wr2 * 16 + ln15) * MUP + kk * 32 + lhi * 8];

  for (int half = 0; half < 2; ++half) {
    f32x4 acc[8] = {};   // col = half*512 + wc2*128 + n*16 + ln15
#pragma unroll
    for (int n = 0; n < 8; ++n) {
      const int cc = half * 512 + wc2 * 128 + n * 16 + ln15;
      f16x8 bb[8];
#pragma unroll
      for (int kk = 0; kk < 8; ++kk)
        bb[kk] = *(const f16x8*)&distT[(size_t)cc * NLEAF + kk * 32 + lhi * 8];
#pragma unroll
      for (int kk = 0; kk < 8; ++kk)
        acc[n] = __builtin_amdgcn_mfma_f32_16x16x32_f16(aa[kk], bb[kk], acc[n], 0, 0, 0);
    }
    const int ncols = (half == 0) ? 512 : (NCLS - 512);
    // two 16-row chunks, assembled in LDS, streamed as full contiguous rows
#pragma unroll
    for (int ch = 0; ch < 2; ++ch) {
      __syncthreads();   // previous chunk's reads (or P-phase) complete
      if (wr2 == ch) {
#pragma unroll
        for (int n = 0; n < 8; ++n)
#pragma unroll
          for (int j = 0; j < 4; ++j)
            sm.C[(lhi * 4 + j) * CSTR + wc2 * 128 + n * 16 + ln15] = acc[n][j];
      }
      __syncthreads();
      // stream 16 rows, 2 rows per wave, contiguous 2KB bursts (plain stores:
      // L2 write-combines into full 64B lines; nt bypassed L2 and 2.15x'd WRITE_SIZE)
#pragma unroll
      for (int rr = 0; rr < 2; ++rr) {
        int lr = wave * 2 + rr;
        size_t gbase = (size_t)(r0 + ch * 16 + lr) * NCLS + half * 512;
#pragma unroll
        for (int i = 0; i < 2; ++i) {
          int q = i * 64 + lane;       // float4 index within half-row
          if (q * 4 < ncols) {
            f32x4 v = *(const f32x4*)&sm.C[lr * CSTR + q * 4];
            *(f32x4*)&out[gbase + q * 4] = v;
          }
        }
      }
    }
  }
#undef P1_LOAD
#undef P1_WRITE
}

extern "C" void kernel_launch(void* const* d_in, const int* in_sizes, int n_in,
                              void* d_out, int out_size, void* d_ws, size_t ws_size,
                              hipStream_t stream) {
  const float* x  = (const float*)d_in[0];   // 16384x512
  const float* gw = (const float*)d_in[1];   // 255x512
  const float* gb = (const float*)d_in[2];   // 255
  const float* ll = (const float*)d_in[3];   // 256x1000
  float* out = (float*)d_out;                // 16384x1000
  char* ws = (char*)d_ws;

  _Float16* gwh   = (_Float16*)(ws);            // 262,144 B
  _Float16* distT = (_Float16*)(ws + 262144);   // 524,288 B

  cvt_gw   <<<128, 256, 0, stream>>>((const float4*)gw, (f16x4*)gwh);
  softmax_t<<<256, 256, 0, stream>>>(ll, distT);
  fused    <<<BATCH / 32, 512, 0, stream>>>(x, gwh, gb, distT, out);
}

// Round 8
// 68.666 us; speedup vs baseline: 1.6923x; 1.6923x over previous
//
#include <hip/hip_runtime.h>

typedef __attribute__((ext_vector_type(8))) _Float16 f16x8;
typedef __attribute__((ext_vector_type(4))) _Float16 f16x4;
typedef __attribute__((ext_vector_type(4))) float   f32x4;

#define BATCH 16384
#define NFEAT 512
#define NCLS  1000
#define NLEAF 256
#define NINT  255
#define LDP   72    // staging LDS row stride (f16)
#define MUP   264   // mu LDS row stride (f16)
#define PSTR  257   // P LDS row stride (f32): odd -> no 4-way write conflict

// ---- convert gate_w (255x512) -> f16 padded to 256x512 (row 255 = 0) ----
__global__ __launch_bounds__(256) void cvt_gw(const float4* __restrict__ in,
                                              f16x4* __restrict__ out) {
  int i = blockIdx.x * 256 + threadIdx.x;
  int row = i >> 7;
  f16x4 o;
  if (row < NINT) {
    float4 v = in[i];
    o[0] = (_Float16)v.x; o[1] = (_Float16)v.y;
    o[2] = (_Float16)v.z; o[3] = (_Float16)v.w;
  } else {
    o[0] = o[1] = o[2] = o[3] = (_Float16)0.f;
  }
  out[i] = o;
}

// ---- softmax of leaf_logits rows -> distF in MFMA-fragment-swizzled layout ----
// element (class c, leaf l) stored at ((c>>4)*8 + l>>5)*64*8 + ((l>>3&3)*16 + (c&15))*8 + (l&7)
// so a wave's B-fragment load (16 classes x k-slice of 32 leaves) is 64 lanes x 16B contiguous.
__global__ __launch_bounds__(256) void softmax_t(const float* __restrict__ L,
                                                 _Float16* __restrict__ distF) {
  __shared__ float red[4];
  const int l = blockIdx.x, t = threadIdx.x;
  const int wave = t >> 6, lane = t & 63;
  const int kt = l >> 5, lhi_l = (l >> 3) & 3, jj = l & 7;
  float v[4];
  const bool live = t < 250;
  if (live) {
    float4 f = *(const float4*)&L[(size_t)l * NCLS + t * 4];
    v[0] = f.x; v[1] = f.y; v[2] = f.z; v[3] = f.w;
  } else {
    v[0] = v[1] = v[2] = v[3] = -1e30f;
  }
  float mx = fmaxf(fmaxf(v[0], v[1]), fmaxf(v[2], v[3]));
#pragma unroll
  for (int s = 32; s; s >>= 1) mx = fmaxf(mx, __shfl_xor(mx, s));
  if (lane == 0) red[wave] = mx;
  __syncthreads();
  mx = fmaxf(fmaxf(red[0], red[1]), fmaxf(red[2], red[3]));
  __syncthreads();
  float e[4], sum = 0.f;
#pragma unroll
  for (int i = 0; i < 4; ++i) { e[i] = __expf(v[i] - mx); sum += e[i]; }
  if (!live) { e[0] = e[1] = e[2] = e[3] = 0.f; sum = 0.f; }
#pragma unroll
  for (int s = 32; s; s >>= 1) sum += __shfl_xor(sum, s);
  if (lane == 0) red[wave] = sum;
  __syncthreads();
  sum = red[0] + red[1] + red[2] + red[3];
  float inv = 1.f / sum;
#pragma unroll
  for (int i = 0; i < 4; ++i) {
    int c = t * 4 + i;                       // t=250..255 -> c=1000..1023 -> zeros
    float val = live ? e[i] * inv : 0.f;
    int c16 = c >> 4, ln = c & 15;
    size_t idx = (((size_t)(c16 * 8 + kt)) * 64 + lhi_l * 16 + ln) * 8 + jj;
    distF[idx] = (_Float16)val;
  }
}

// ---- fused: gemm1 + sigmoid + tree + gemm2 (coalesced fragment B-loads) ----
// BM=64 rows/block, 256 blocks (1/CU), 512 threads (8 waves).
__global__ __launch_bounds__(512)
void fused(const float* __restrict__ x, const _Float16* __restrict__ gwh,
           const float* __restrict__ gb, const _Float16* __restrict__ distF,
           float* __restrict__ out) {
  __shared__ union {
    struct { _Float16 A[64 * LDP]; _Float16 B[256 * LDP]; } s;  // 46,080 B
    float P[64 * PSTR];                                         // 65,792 B
  } sm;
  __shared__ _Float16 sMu[64 * MUP];                            // 33,792 B

  const int tid  = threadIdx.x;
  const int wave = tid >> 6, lane = tid & 63;
  const int ln15 = lane & 15, lhi = lane >> 4;
  const int wr = wave >> 2, wc = wave & 3;      // phase1: 2x4 waves, 32r x 64c
  const int r0 = blockIdx.x * 64;

  float bias_[4];
#pragma unroll
  for (int n = 0; n < 4; ++n) {
    int col = wc * 64 + n * 16 + ln15;
    bias_[n] = (col < NINT) ? gb[col] : 0.f;
  }

  // ---------------- phase 1: logits = x @ gwh^T (2-deep reg prefetch) ----------------
  f32x4 acc1[2][4] = {};
  const int arow = tid >> 4, acol = (tid & 15) * 4;  // A: 2 float4/thread
  const int brow = tid >> 3, bcol = (tid & 7) * 8;   // B: 4 uint4/thread

  float4 pa_[2], pa2_[2];
  uint4  pb_[2][4];

#define P1_LOAD(s, k0)                                                           \
  {                                                                              \
    pa_[s]  = *(const float4*)&x[(size_t)(r0 + arow) * NFEAT + (k0) + acol];     \
    pa2_[s] = *(const float4*)&x[(size_t)(r0 + 32 + arow) * NFEAT + (k0) + acol];\
    _Pragma("unroll")                                                            \
    for (int i = 0; i < 4; ++i)                                                  \
      pb_[s][i] = *(const uint4*)&gwh[(size_t)(i * 64 + brow) * NFEAT + (k0) + bcol];\
  }
#define P1_WRITE(s)                                                              \
  {                                                                              \
    f16x4 h;                                                                     \
    h[0] = (_Float16)pa_[s].x; h[1] = (_Float16)pa_[s].y;                        \
    h[2] = (_Float16)pa_[s].z; h[3] = (_Float16)pa_[s].w;                        \
    *(f16x4*)&sm.s.A[arow * LDP + acol] = h;                                     \
    h[0] = (_Float16)pa2_[s].x; h[1] = (_Float16)pa2_[s].y;                      \
    h[2] = (_Float16)pa2_[s].z; h[3] = (_Float16)pa2_[s].w;                      \
    *(f16x4*)&sm.s.A[(32 + arow) * LDP + acol] = h;                              \
    _Pragma("unroll")                                                            \
    for (int i = 0; i < 4; ++i)                                                  \
      *(uint4*)&sm.s.B[(i * 64 + brow) * LDP + bcol] = pb_[s][i];                \
  }

  P1_LOAD(0, 0);
  P1_LOAD(1, 64);
#pragma unroll
  for (int k = 0; k < NFEAT / 64; ++k) {       // fully unrolled: s is compile-time
    const int s = k & 1;
    P1_WRITE(s);                               // partial vmcnt: only set s's loads
    __syncthreads();
    if (k + 2 < NFEAT / 64) P1_LOAD(s, (k + 2) * 64);   // 2-deep: flies over 2 iters
#pragma unroll
    for (int kk = 0; kk < 2; ++kk) {
      f16x8 a[2], b[4];
#pragma unroll
      for (int m = 0; m < 2; ++m)
        a[m] = *(const f16x8*)&sm.s.A[(wr * 32 + m * 16 + ln15) * LDP + kk * 32 + lhi * 8];
#pragma unroll
      for (int n = 0; n < 4; ++n)
        b[n] = *(const f16x8*)&sm.s.B[(wc * 64 + n * 16 + ln15) * LDP + kk * 32 + lhi * 8];
#pragma unroll
      for (int m = 0; m < 2; ++m)
#pragma unroll
        for (int n = 0; n < 4; ++n)
          acc1[m][n] = __builtin_amdgcn_mfma_f32_16x16x32_f16(a[m], b[n], acc1[m][n], 0, 0, 0);
    }
    __syncthreads();
  }

  // ---------------- phase 2a: sigmoid -> P (LDS, stride 257) ----------------
#pragma unroll
  for (int m = 0; m < 2; ++m)
#pragma unroll
    for (int n = 0; n < 4; ++n) {
      int col = wc * 64 + n * 16 + ln15;
#pragma unroll
      for (int j = 0; j < 4; ++j) {
        int rl = wr * 32 + m * 16 + lhi * 4 + j;
        float v = acc1[m][n][j] + bias_[n];
        sm.P[rl * PSTR + col] = 1.f / (1.f + __expf(-v));
      }
    }
  __syncthreads();

  // ---------------- phase 2b: tree product -> sMu ----------------
  const int lf = lane * 4;
#pragma unroll
  for (int rr = 0; rr < 8; ++rr) {
    int row = wave * 8 + rr;
    const float* p = &sm.P[row * PSTR];
    float pre = 1.f;
#pragma unroll
    for (int d = 0; d < 6; ++d) {
      int node = (1 << d) - 1 + (lf >> (8 - d));
      int bit  = (lf >> (7 - d)) & 1;
      float g = p[node];
      pre *= bit ? g : (1.f - g);
    }
    float g6  = p[63 + lane];
    float g7a = p[127 + 2 * lane];
    float g7b = p[128 + 2 * lane];
    f16x4 o;
    o[0] = (_Float16)(pre * (1.f - g6) * (1.f - g7a));
    o[1] = (_Float16)(pre * (1.f - g6) * g7a);
    o[2] = (_Float16)(pre * g6 * (1.f - g7b));
    o[3] = (_Float16)(pre * g6 * g7b);
    *(f16x4*)&sMu[row * MUP + lf] = o;
  }
  __syncthreads();

  // ---------------- phase 3: out = mu @ dist^T, B-frags coalesced from distF ----------------
  const int wr2 = wave >> 2, wc2 = wave & 3;   // rows wr2*32..+32, cols ct*128+wc2*32..+32
  for (int ct = 0; ct < 8; ++ct) {
    const int c16 = ct * 8 + wc2 * 2;
    f16x8 bb0[8], bb1[8];
#pragma unroll
    for (int kk = 0; kk < 8; ++kk) {           // each load: 64 lanes x 16B = 1KB contiguous
      bb0[kk] = *(const f16x8*)&distF[(((size_t)(c16    ) * 8 + kk) * 64 + lane) * 8];
      bb1[kk] = *(const f16x8*)&distF[(((size_t)(c16 + 1) * 8 + kk) * 64 + lane) * 8];
    }
    f32x4 a00 = {}, a01 = {}, a10 = {}, a11 = {};
#pragma unroll
    for (int kk = 0; kk < 8; ++kk) {
      f16x8 a0 = *(const f16x8*)&sMu[(wr2 * 32 + ln15) * MUP + kk * 32 + lhi * 8];
      f16x8 a1 = *(const f16x8*)&sMu[(wr2 * 32 + 16 + ln15) * MUP + kk * 32 + lhi * 8];
      a00 = __builtin_amdgcn_mfma_f32_16x16x32_f16(a0, bb0[kk], a00, 0, 0, 0);
      a01 = __builtin_amdgcn_mfma_f32_16x16x32_f16(a0, bb1[kk], a01, 0, 0, 0);
      a10 = __builtin_amdgcn_mfma_f32_16x16x32_f16(a1, bb0[kk], a10, 0, 0, 0);
      a11 = __builtin_amdgcn_mfma_f32_16x16x32_f16(a1, bb1[kk], a11, 0, 0, 0);
    }
    int col0 = ct * 128 + wc2 * 32 + ln15;
    int col1 = col0 + 16;
    int rbase = r0 + wr2 * 32 + lhi * 4;
    if (col0 < NCLS) {
#pragma unroll
      for (int j = 0; j < 4; ++j) {
        out[(size_t)(rbase + j) * NCLS + col0]      = a00[j];
        out[(size_t)(rbase + 16 + j) * NCLS + col0] = a10[j];
      }
    }
    if (col1 < NCLS) {
#pragma unroll
      for (int j = 0; j < 4; ++j) {
        out[(size_t)(rbase + j) * NCLS + col1]      = a01[j];
        out[(size_t)(rbase + 16 + j) * NCLS + col1] = a11[j];
      }
    }
  }
#undef P1_LOAD
#undef P1_WRITE
}

extern "C" void kernel_launch(void* const* d_in, const int* in_sizes, int n_in,
                              void* d_out, int out_size, void* d_ws, size_t ws_size,
                              hipStream_t stream) {
  const float* x  = (const float*)d_in[0];   // 16384x512
  const float* gw = (const float*)d_in[1];   // 255x512
  const float* gb = (const float*)d_in[2];   // 255
  const float* ll = (const float*)d_in[3];   // 256x1000
  float* out = (float*)d_out;                // 16384x1000
  char* ws = (char*)d_ws;

  _Float16* gwh   = (_Float16*)(ws);            // 262,144 B
  _Float16* distF = (_Float16*)(ws + 262144);   // 524,288 B (1024x256 swizzled)

  cvt_gw   <<<128, 256, 0, stream>>>((const float4*)gw, (f16x4*)gwh);
  softmax_t<<<256, 256, 0, stream>>>(ll, distF);
  fused    <<<BATCH / 64, 512, 0, stream>>>(x, gwh, gb, distF, out);
}